// Round 4
// baseline (1212.626 us; speedup 1.0000x reference)
//
#include <hip/hip_runtime.h>
#include <hip/hip_fp16.h>

constexpr int N_USERS = 50000;
constexpr int N_ENT   = 100000;
constexpr int N_NODES = 150000;
constexpr int N_EDGES = 2400000;
constexpr int OUT_D   = 176;               // 64 + 64 + 32 + 16

// ---------------------------------------------------------------------------
// init: out[:,0:64) = concat(ue,ee);  xh = fp16 copy (dense [N][64], 128B rows)
// ---------------------------------------------------------------------------
__global__ __launch_bounds__(256) void init_x_kernel(const float* __restrict__ ue,
                                                     const float* __restrict__ ee,
                                                     float* __restrict__ out,
                                                     __half* __restrict__ xh) {
    int tid = blockIdx.x * 256 + threadIdx.x;    // over N_NODES * 16 float4s
    int n = tid >> 4, q = tid & 15;
    const float* src = (n < N_USERS) ? ue + (size_t)n * 64
                                     : ee + (size_t)(n - N_USERS) * 64;
    float4 v = *(const float4*)(src + q * 4);
    *(float4*)(out + (size_t)n * OUT_D + q * 4) = v;
    union { __half2 h[2]; uint2 u; } pk;
    pk.h[0] = __floats2half2_rn(v.x, v.y);
    pk.h[1] = __floats2half2_rn(v.z, v.w);
    *(uint2*)(xh + (size_t)n * 64 + q * 4) = pk.u;
}

// fp32 slab column block -> dense fp16 shadow ([N][DIN]); 2 dims per thread
__global__ __launch_bounds__(256) void conv_kernel(const float* __restrict__ src,
                                                   __half* __restrict__ xh, int DIN) {
    int tid = blockIdx.x * 256 + threadIdx.x;    // over N_NODES * DIN/2
    int n = tid / (DIN / 2), t = tid % (DIN / 2);
    float2 v = *(const float2*)(src + (size_t)n * OUT_D + 2 * t);
    *(__half2*)(xh + (size_t)n * DIN + 2 * t) = __floats2half2_rn(v.x, v.y);
}

// ---------------------------------------------------------------------------
// CSR construction: histogram -> in-place exclusive scan -> counting sort.
// After build, cursor[n] == start[n+1]; start[n] = (n ? cursor[n-1] : 0).
// ---------------------------------------------------------------------------
__global__ __launch_bounds__(256) void hist_kernel(const int* __restrict__ er,
                                                   int* __restrict__ cnt) {
    int e = blockIdx.x * 256 + threadIdx.x;      // N_EDGES % 256 == 0
    atomicAdd(&cnt[er[e]], 1);
}

__global__ __launch_bounds__(1024) void scan_kernel(int* __restrict__ cursor) {
    __shared__ int wtot[16];
    __shared__ int carry_s;
    int tid = threadIdx.x;
    int lane = tid & 63, w = tid >> 6;
    if (tid == 0) carry_s = 0;
    __syncthreads();
    for (int base = 0; base < N_NODES; base += 1024) {
        int i = base + tid;
        int v = (i < N_NODES) ? cursor[i] : 0;
        int incl = v;
        #pragma unroll
        for (int off = 1; off < 64; off <<= 1) {
            int t = __shfl_up(incl, off);
            if (lane >= off) incl += t;
        }
        if (lane == 63) wtot[w] = incl;
        __syncthreads();
        int woff = 0, total = 0;
        #pragma unroll
        for (int k = 0; k < 16; ++k) {
            int tk = wtot[k];
            if (k < w) woff += tk;
            total += tk;
        }
        if (i < N_NODES) cursor[i] = carry_s + woff + incl - v;  // exclusive
        __syncthreads();
        if (tid == 0) carry_s += total;
        __syncthreads();
    }
}

__global__ __launch_bounds__(256) void build_csr_kernel(const float* __restrict__ ev,
                                                        const int*   __restrict__ er,
                                                        const int*   __restrict__ ec,
                                                        int*    __restrict__ cursor,
                                                        int*    __restrict__ cols,
                                                        __half* __restrict__ vals) {
    int e = blockIdx.x * 256 + threadIdx.x;      // N_EDGES % 256 == 0
    int pos = atomicAdd(&cursor[er[e]], 1);
    cols[pos] = ec[e];
    vals[pos] = __float2half(ev[e]);
}

// ---------------------------------------------------------------------------
// Fused layer. One wave per node. Gather from fp16 shadow xh ([N][DIN]):
// NE = 128/DIN edges per wave-instruction, each lane reads half2 (2 dims).
// 4 gather instructions in flight. Then a=x+side, b=x*side, dense + norm.
// ---------------------------------------------------------------------------
template<int DIN, int DOUT>
__global__ __launch_bounds__(256, 8) void fused_layer_kernel(
        const int*    __restrict__ cursor,
        const int*    __restrict__ cols,
        const __half* __restrict__ vals,
        const __half* __restrict__ xh,
        float* __restrict__ out,
        const float* __restrict__ Wgc, const float* __restrict__ bgc,
        const float* __restrict__ Wbi, const float* __restrict__ bbi,
        int cin, int cout) {
    __shared__ float as[4][DIN];
    __shared__ float bs[4][DIN];

    int tid = threadIdx.x;
    int w = tid >> 6, lane = tid & 63;
    int n = blockIdx.x * 4 + w;

    constexpr int HP = DIN / 2;         // half2 elements per row
    constexpr int NE = 128 / DIN;       // edges per wave-gather (2 or 4)
    int g = lane / HP;                  // edge slot
    int t = lane % HP;                  // dim-pair index

    int s = n ? cursor[n - 1] : 0;
    int e_end = cursor[n];
    const __half2* xr = (const __half2*)xh;

    float accx = 0.f, accy = 0.f;
    int e = s;
    for (; e + 4 * NE <= e_end; e += 4 * NE) {
        int c0 = cols[e + 0 * NE + g];
        int c1 = cols[e + 1 * NE + g];
        int c2 = cols[e + 2 * NE + g];
        int c3 = cols[e + 3 * NE + g];
        float v0 = __half2float(vals[e + 0 * NE + g]);
        float v1 = __half2float(vals[e + 1 * NE + g]);
        float v2 = __half2float(vals[e + 2 * NE + g]);
        float v3 = __half2float(vals[e + 3 * NE + g]);
        float2 f0 = __half22float2(xr[(size_t)c0 * HP + t]);
        float2 f1 = __half22float2(xr[(size_t)c1 * HP + t]);
        float2 f2 = __half22float2(xr[(size_t)c2 * HP + t]);
        float2 f3 = __half22float2(xr[(size_t)c3 * HP + t]);
        accx += v0 * f0.x; accy += v0 * f0.y;
        accx += v1 * f1.x; accy += v1 * f1.y;
        accx += v2 * f2.x; accy += v2 * f2.y;
        accx += v3 * f3.x; accy += v3 * f3.y;
    }
    for (; e < e_end; e += NE) {
        int idx = e + g;
        bool ok = idx < e_end;
        int cc = ok ? cols[idx] : cols[e];
        float vv = ok ? __half2float(vals[idx]) : 0.f;
        float2 ff = __half22float2(xr[(size_t)cc * HP + t]);
        accx += vv * ff.x; accy += vv * ff.y;
    }
    // fold edge slots down to slot 0 (lanes 0..HP-1)
    #pragma unroll
    for (int m = 32; m >= HP; m >>= 1) {
        accx += __shfl_xor(accx, m);
        accy += __shfl_xor(accy, m);
    }

    if (lane < HP) {
        float2 xv = *(const float2*)(out + (size_t)n * OUT_D + cin + 2 * lane);
        as[w][2 * lane]     = xv.x + accx;
        as[w][2 * lane + 1] = xv.y + accy;
        bs[w][2 * lane]     = xv.x * accx;
        bs[w][2 * lane + 1] = xv.y * accy;
    }
    __syncthreads();

    float h = 0.f;
    if (lane < DOUT) {
        float ag = bgc[lane], ab = bbi[lane];
        #pragma unroll 16
        for (int i = 0; i < DIN; ++i) {
            ag += as[w][i] * Wgc[i * DOUT + lane];
            ab += bs[w][i] * Wbi[i * DOUT + lane];
        }
        ag = ag > 0.f ? ag : 0.01f * ag;   // leaky_relu slope 0.01
        ab = ab > 0.f ? ab : 0.01f * ab;
        h = ag + ab;
    }
    float ss = h * h;
    #pragma unroll
    for (int off = 32; off; off >>= 1) ss += __shfl_xor(ss, off);

    if (lane < DOUT) {
        float inv = 1.f / fmaxf(sqrtf(ss), 1e-12f);
        out[(size_t)n * OUT_D + cout + lane] = h * inv;
    }
}

extern "C" void kernel_launch(void* const* d_in, const int* in_sizes, int n_in,
                              void* d_out, int out_size, void* d_ws, size_t ws_size,
                              hipStream_t stream) {
    const float* ue = (const float*)d_in[0];
    const float* ee = (const float*)d_in[1];
    const float* ev = (const float*)d_in[2];
    const int*   er = (const int*)d_in[3];
    const int*   ec = (const int*)d_in[4];
    float* out = (float*)d_out;

    // ws layout: xh [N*64 half = 19.2MB] | cols [E int = 9.6MB] |
    //            vals [E half = 4.8MB] | cursor [N int = 0.6MB]  -> 34.2MB
    __half* xh     = (__half*)d_ws;
    int*    cols   = (int*)((char*)d_ws + (size_t)N_NODES * 64 * 2);
    __half* vals   = (__half*)((char*)cols + (size_t)N_EDGES * 4);
    int*    cursor = (int*)((char*)vals + (size_t)N_EDGES * 2);

    init_x_kernel<<<(N_NODES * 16) / 256, 256, 0, stream>>>(ue, ee, out, xh);

    hipMemsetAsync(cursor, 0, (size_t)N_NODES * sizeof(int), stream);
    hist_kernel<<<N_EDGES / 256, 256, 0, stream>>>(er, cursor);
    scan_kernel<<<1, 1024, 0, stream>>>(cursor);
    build_csr_kernel<<<N_EDGES / 256, 256, 0, stream>>>(ev, er, ec, cursor, cols, vals);

    // layer 0: din=64 dout=64, x fp32 at col 0, write col 64
    fused_layer_kernel<64, 64><<<N_NODES / 4, 256, 0, stream>>>(cursor, cols, vals, xh, out,
        (const float*)d_in[5], (const float*)d_in[6],
        (const float*)d_in[7], (const float*)d_in[8], 0, 64);
    conv_kernel<<<(N_NODES * 32) / 256, 256, 0, stream>>>(out + 64, xh, 64);

    // layer 1: din=64 dout=32, x at col 64, write col 128
    fused_layer_kernel<64, 32><<<N_NODES / 4, 256, 0, stream>>>(cursor, cols, vals, xh, out,
        (const float*)d_in[9], (const float*)d_in[10],
        (const float*)d_in[11], (const float*)d_in[12], 64, 128);
    conv_kernel<<<(N_NODES * 16) / 256, 256, 0, stream>>>(out + 128, xh, 32);

    // layer 2: din=32 dout=16, x at col 128, write col 160
    fused_layer_kernel<32, 16><<<N_NODES / 4, 256, 0, stream>>>(cursor, cols, vals, xh, out,
        (const float*)d_in[13], (const float*)d_in[14],
        (const float*)d_in[15], (const float*)d_in[16], 128, 160);
}